// Round 1
// baseline (366.606 us; speedup 1.0000x reference)
//
#include <hip/hip_runtime.h>
#include <hip/hip_bf16.h>

// Problem constants
// B=4, N=1024, M=4096, DQ=DC=1024, H=16, DH=64, INNER=1024, SCALE=0.125

typedef __attribute__((ext_vector_type(8))) short short8;          // 8 bf16 (MFMA A/B frag)
typedef __attribute__((ext_vector_type(8))) unsigned short u16x8;
typedef __attribute__((ext_vector_type(4))) float f32x4;

static __device__ __forceinline__ void gload_lds16(const void* g, void* l) {
  __builtin_amdgcn_global_load_lds((const __attribute__((address_space(1))) void*)g,
                                   (__attribute__((address_space(3))) void*)l, 16, 0, 0);
}

static __device__ __forceinline__ unsigned short f2bf(float f) {
  __hip_bfloat16 h = __float2bfloat16(f);
  unsigned short u;
  __builtin_memcpy(&u, &h, 2);
  return u;
}

// ---------------- cast fp32 -> bf16, 8 elems/thread ----------------
__global__ __launch_bounds__(256) void cast_bf16_kernel(const float* __restrict__ in,
                                                        unsigned short* __restrict__ out,
                                                        int n8) {
  int idx = blockIdx.x * 256 + threadIdx.x;
  int stride = gridDim.x * 256;
  for (int i = idx; i < n8; i += stride) {
    const float4* p = (const float4*)in + (size_t)i * 2;
    float4 a = p[0], b = p[1];
    u16x8 r;
    r[0] = f2bf(a.x); r[1] = f2bf(a.y); r[2] = f2bf(a.z); r[3] = f2bf(a.w);
    r[4] = f2bf(b.x); r[5] = f2bf(b.y); r[6] = f2bf(b.z); r[7] = f2bf(b.w);
    *((u16x8*)out + i) = r;
  }
}

// ---------------- transpose + cast: W[K][N] fp32 -> Wt[N][K] bf16 ----------------
__global__ __launch_bounds__(256) void transpose_cast_kernel(const float* __restrict__ W,
                                                             unsigned short* __restrict__ Wt,
                                                             int K, int N) {
  __shared__ float tile[32][33];
  int n0 = blockIdx.x * 32, k0 = blockIdx.y * 32;
  int tx = threadIdx.x & 31, ty = threadIdx.x >> 5;
#pragma unroll
  for (int r = 0; r < 32; r += 8)
    tile[ty + r][tx] = W[(size_t)(k0 + ty + r) * N + n0 + tx];
  __syncthreads();
#pragma unroll
  for (int r = 0; r < 32; r += 8)
    Wt[(size_t)(n0 + ty + r) * K + k0 + tx] = f2bf(tile[tx][ty + r]);
}

// ---------------- GEMM: C[M,N] = A[M,K](bf16,row) * Bt[N,K](bf16,row)^T ----------------
// 128x128 tile, BK=64, 4 waves, each wave 64x64. XOR-swizzled LDS (pre-swizzled
// global source so global_load_lds stays linear).
// EPI 0: write Q layout [b(=row>>10)][h][n][64] bf16 into out0
// EPI 1: write K ([b(=row>>12)][h][m][64]) for col<1024 into out0, V likewise into out1
// EPI 2: write fp32 outF[row*1024+col] = acc + bias[col]
template <int EPI>
__global__ __launch_bounds__(256, 2) void gemm_bt_kernel(
    const unsigned short* __restrict__ A, const unsigned short* __restrict__ Bt,
    int M, int N, int K,
    unsigned short* __restrict__ out0, unsigned short* __restrict__ out1,
    float* __restrict__ outF, const float* __restrict__ bias) {
  __shared__ unsigned short As[128 * 64];
  __shared__ unsigned short Bs[128 * 64];
  const int tid = threadIdx.x;
  const int l = tid & 63;
  const int lq = l & 15, g = l >> 4;
  const int w = tid >> 6;
  const int wr = w >> 1, wc = w & 1;
  const int m0 = blockIdx.y * 128, n0 = blockIdx.x * 128;

  f32x4 acc[4][4] = {};

  for (int k0 = 0; k0 < K; k0 += 64) {
    __syncthreads();
#pragma unroll
    for (int t = 0; t < 4; ++t) {
      int c = t * 256 + tid;
      int row = c >> 3, cb = c & 7;
      int srcoff = (cb * 16) ^ ((row & 7) << 4);
      char* la = (char*)As + t * 4096 + (tid & 192) * 16;  // wave-uniform base
      gload_lds16((const char*)(A + (size_t)(m0 + row) * K + k0) + srcoff, la);
      char* lb = (char*)Bs + t * 4096 + (tid & 192) * 16;
      gload_lds16((const char*)(Bt + (size_t)(n0 + row) * K + k0) + srcoff, lb);
    }
    __syncthreads();
#pragma unroll
    for (int ks = 0; ks < 2; ++ks) {
      short8 af[4], bfr[4];
#pragma unroll
      for (int mt = 0; mt < 4; ++mt) {
        int row = wr * 64 + mt * 16 + lq;
        af[mt] = *(const short8*)&As[row * 64 + ((ks * 32 + g * 8) ^ ((row & 7) << 3))];
      }
#pragma unroll
      for (int nt = 0; nt < 4; ++nt) {
        int row = wc * 64 + nt * 16 + lq;
        bfr[nt] = *(const short8*)&Bs[row * 64 + ((ks * 32 + g * 8) ^ ((row & 7) << 3))];
      }
#pragma unroll
      for (int mt = 0; mt < 4; ++mt)
#pragma unroll
        for (int nt = 0; nt < 4; ++nt)
          acc[mt][nt] =
              __builtin_amdgcn_mfma_f32_16x16x32_bf16(af[mt], bfr[nt], acc[mt][nt], 0, 0, 0);
    }
  }

#pragma unroll
  for (int mt = 0; mt < 4; ++mt) {
#pragma unroll
    for (int nt = 0; nt < 4; ++nt) {
#pragma unroll
      for (int r = 0; r < 4; ++r) {
        int row = m0 + wr * 64 + mt * 16 + g * 4 + r;
        int col = n0 + wc * 64 + nt * 16 + lq;
        float v = acc[mt][nt][r];
        if (EPI == 0) {
          int b = row >> 10, nq = row & 1023;
          int h = col >> 6, d = col & 63;
          out0[(((size_t)(b * 16 + h)) * 1024 + nq) * 64 + d] = f2bf(v);
        } else if (EPI == 1) {
          int b = row >> 12, mm = row & 4095;
          int hv = col & 1023;
          int h = hv >> 6, d = hv & 63;
          unsigned short* dst = (col < 1024) ? out0 : out1;
          dst[(((size_t)(b * 16 + h)) * 4096 + mm) * 64 + d] = f2bf(v);
        } else {
          outF[(size_t)row * 1024 + col] = v + bias[col];
        }
      }
    }
  }
}

// ---------------- fused attention ----------------
// Grid: (8 q-blocks, 64 bh). Block: 256 thr = 4 waves, each wave 32 q-rows.
// Scores are clipped to [-5,5] (masked -> exactly -5), so softmax needs no
// running max: P = exp(s), denom = sum P. KVBLK = 64.
__global__ __launch_bounds__(256, 2) void attn_kernel(
    const unsigned short* __restrict__ Q, const unsigned short* __restrict__ Kb,
    const unsigned short* __restrict__ Vb, const int* __restrict__ mask,
    unsigned short* __restrict__ Ob) {
  __shared__ unsigned short Ks[64 * 64];   // [j][d], XOR-swizzled content
  __shared__ unsigned short Vt[64 * 64];   // [d][j], XOR-swizzled
  __shared__ unsigned short Ps[4 * 32 * 64];  // per-wave [q][j], XOR-swizzled

  const int tid = threadIdx.x;
  const int l = tid & 63, w = tid >> 6;
  const int lq = l & 15, g = l >> 4;
  const int bh = blockIdx.y;
  const int b = bh >> 4, h = bh & 15;
  const int q0 = blockIdx.x * 128 + w * 32;

  const unsigned short* Qh = Q + (size_t)bh * 1024 * 64;
  const unsigned short* Kh = Kb + (size_t)bh * 4096 * 64;
  const unsigned short* Vh = Vb + (size_t)bh * 4096 * 64;
  const int* mb = mask + b * 4096;

  // Q fragments live in registers for the whole kernel
  short8 qf[2][2];
#pragma unroll
  for (int mt = 0; mt < 2; ++mt)
#pragma unroll
    for (int ks = 0; ks < 2; ++ks)
      qf[mt][ks] = *(const short8*)&Qh[(size_t)(q0 + mt * 16 + lq) * 64 + ks * 32 + g * 8];

  f32x4 acc[2][4] = {};
  float denom[2][4] = {};
  unsigned short* Pw = &Ps[w * 2048];

  for (int jt = 0; jt < 64; ++jt) {
    const int j0 = jt * 64;
    __syncthreads();  // previous tile fully consumed
    // stage K tile [64][64] via global_load_lds, source pre-swizzled
#pragma unroll
    for (int t = 0; t < 2; ++t) {
      int c = t * 256 + tid;
      int j = c >> 3, cb = c & 7;
      int srcoff = (cb * 16) ^ ((j & 7) << 4);
      char* lk = (char*)Ks + t * 4096 + (tid & 192) * 16;
      gload_lds16((const char*)(Kh + (size_t)(j0 + j) * 64) + srcoff, lk);
    }
    // stage V transposed: reg -> swizzled ds_write
#pragma unroll
    for (int t = 0; t < 2; ++t) {
      int c = t * 256 + tid;
      int j = c >> 3, dc = c & 7;
      u16x8 vv = *(const u16x8*)&Vh[(size_t)(j0 + j) * 64 + dc * 8];
#pragma unroll
      for (int e = 0; e < 8; ++e) {
        int d = dc * 8 + e;
        Vt[d * 64 + (j ^ ((d & 7) << 3))] = vv[e];
      }
    }
    // per-lane mask for its j columns
    int mk[4];
#pragma unroll
    for (int nt = 0; nt < 4; ++nt) mk[nt] = mb[j0 + nt * 16 + lq];
    __syncthreads();

    // K fragments
    short8 kf[4][2];
#pragma unroll
    for (int nt = 0; nt < 4; ++nt) {
      int row = nt * 16 + lq;
#pragma unroll
      for (int ks = 0; ks < 2; ++ks)
        kf[nt][ks] = *(const short8*)&Ks[row * 64 + ((ks * 32 + g * 8) ^ ((row & 7) << 3))];
    }

    float tmp[2][4] = {};
#pragma unroll
    for (int mt = 0; mt < 2; ++mt) {
#pragma unroll
      for (int nt = 0; nt < 4; ++nt) {
        f32x4 s = {};
        s = __builtin_amdgcn_mfma_f32_16x16x32_bf16(qf[mt][0], kf[nt][0], s, 0, 0, 0);
        s = __builtin_amdgcn_mfma_f32_16x16x32_bf16(qf[mt][1], kf[nt][1], s, 0, 0, 0);
#pragma unroll
        for (int r = 0; r < 4; ++r) {
          float v = s[r] * 0.125f;
          v = fminf(fmaxf(v, -5.0f), 5.0f);
          v = mk[nt] ? v : -5.0f;  // masked -> exactly -5 (matches ref clip-after-mask)
          float p = __expf(v);
          tmp[mt][r] += p;
          int q = mt * 16 + g * 4 + r;
          int j = nt * 16 + lq;
          Pw[q * 64 + (j ^ ((q & 7) << 3))] = f2bf(p);
        }
      }
    }
    // denominator: reduce over the 16-lane j-group
#pragma unroll
    for (int mt = 0; mt < 2; ++mt)
#pragma unroll
      for (int r = 0; r < 4; ++r) {
        float v = tmp[mt][r];
        v += __shfl_xor(v, 1);
        v += __shfl_xor(v, 2);
        v += __shfl_xor(v, 4);
        v += __shfl_xor(v, 8);
        denom[mt][r] += v;
      }

    // PV
    short8 pa[2][2], vbf[4][2];
#pragma unroll
    for (int mt = 0; mt < 2; ++mt) {
      int row = mt * 16 + lq;
#pragma unroll
      for (int ks = 0; ks < 2; ++ks)
        pa[mt][ks] = *(const short8*)&Pw[row * 64 + ((ks * 32 + g * 8) ^ ((row & 7) << 3))];
    }
#pragma unroll
    for (int dt = 0; dt < 4; ++dt) {
      int row = dt * 16 + lq;
#pragma unroll
      for (int ks = 0; ks < 2; ++ks)
        vbf[dt][ks] = *(const short8*)&Vt[row * 64 + ((ks * 32 + g * 8) ^ ((row & 7) << 3))];
    }
#pragma unroll
    for (int mt = 0; mt < 2; ++mt)
#pragma unroll
      for (int dt = 0; dt < 4; ++dt) {
        acc[mt][dt] = __builtin_amdgcn_mfma_f32_16x16x32_bf16(pa[mt][0], vbf[dt][0], acc[mt][dt], 0, 0, 0);
        acc[mt][dt] = __builtin_amdgcn_mfma_f32_16x16x32_bf16(pa[mt][1], vbf[dt][1], acc[mt][dt], 0, 0, 0);
      }
  }

  // out = num/denom, write [b][q][h*64+d] bf16
#pragma unroll
  for (int mt = 0; mt < 2; ++mt)
#pragma unroll
    for (int dt = 0; dt < 4; ++dt)
#pragma unroll
      for (int r = 0; r < 4; ++r) {
        int qg = q0 + mt * 16 + g * 4 + r;
        int col = h * 64 + dt * 16 + lq;
        float o = acc[mt][dt][r] / denom[mt][r];
        Ob[((size_t)(b * 1024 + qg)) * 1024 + col] = f2bf(o);
      }
}

// ---------------- launcher ----------------
extern "C" void kernel_launch(void* const* d_in, const int* in_sizes, int n_in,
                              void* d_out, int out_size, void* d_ws, size_t ws_size,
                              hipStream_t stream) {
  (void)in_sizes; (void)n_in; (void)out_size; (void)ws_size;
  const float* x    = (const float*)d_in[0];
  const float* ctx  = (const float*)d_in[1];
  const int*   mask = (const int*)d_in[2];
  const float* Wq   = (const float*)d_in[3];
  const float* Wkv  = (const float*)d_in[4];
  const float* Wo   = (const float*)d_in[5];
  const float* bo   = (const float*)d_in[6];
  float* out = (float*)d_out;

  char* ws = (char*)d_ws;
  const size_t MB = 1 << 20;
  unsigned short* xb   = (unsigned short*)(ws + 0);        // 8 MiB  : x bf16 [4096][1024]
  unsigned short* cb   = (unsigned short*)(ws + 8 * MB);   // 32 MiB : ctx bf16 [16384][1024]
  unsigned short* WqT  = (unsigned short*)(ws + 40 * MB);  // 2 MiB
  unsigned short* WkvT = (unsigned short*)(ws + 42 * MB);  // 4 MiB
  unsigned short* WoT  = (unsigned short*)(ws + 46 * MB);  // 2 MiB
  unsigned short* Qb   = (unsigned short*)(ws + 48 * MB);  // 8 MiB  : [b][h][1024][64]
  unsigned short* Kb   = (unsigned short*)(ws + 56 * MB);  // 32 MiB : [b][h][4096][64]
  unsigned short* Vb   = (unsigned short*)(ws + 88 * MB);  // 32 MiB : [b][h][4096][64]
  unsigned short* Ob   = (unsigned short*)(ws + 120 * MB); // 8 MiB  : [b][n][1024]

  cast_bf16_kernel<<<2048, 256, 0, stream>>>(x, xb, (4 * 1024 * 1024) / 8);
  cast_bf16_kernel<<<2048, 256, 0, stream>>>(ctx, cb, (16 * 1024 * 1024) / 8);
  transpose_cast_kernel<<<dim3(32, 32), 256, 0, stream>>>(Wq, WqT, 1024, 1024);
  transpose_cast_kernel<<<dim3(64, 32), 256, 0, stream>>>(Wkv, WkvT, 1024, 2048);
  transpose_cast_kernel<<<dim3(32, 32), 256, 0, stream>>>(Wo, WoT, 1024, 1024);

  gemm_bt_kernel<0><<<dim3(8, 32), 256, 0, stream>>>(xb, WqT, 4096, 1024, 1024,
                                                     Qb, (unsigned short*)nullptr,
                                                     (float*)nullptr, (const float*)nullptr);
  gemm_bt_kernel<1><<<dim3(16, 128), 256, 0, stream>>>(cb, WkvT, 16384, 2048, 1024,
                                                       Kb, Vb,
                                                       (float*)nullptr, (const float*)nullptr);
  attn_kernel<<<dim3(8, 64), 256, 0, stream>>>(Qb, Kb, Vb, mask, Ob);
  gemm_bt_kernel<2><<<dim3(8, 32), 256, 0, stream>>>(Ob, WoT, 4096, 1024, 1024,
                                                     (unsigned short*)nullptr, (unsigned short*)nullptr,
                                                     out, bo);
}

// Round 2
// 311.620 us; speedup vs baseline: 1.1765x; 1.1765x over previous
//
#include <hip/hip_runtime.h>
#include <hip/hip_bf16.h>

// Problem constants
// B=4, N=1024, M=4096, DQ=DC=1024, H=16, DH=64, INNER=1024, SCALE=0.125

typedef __attribute__((ext_vector_type(8))) short short8;          // 8 bf16 (MFMA A/B frag)
typedef __attribute__((ext_vector_type(8))) unsigned short u16x8;
typedef __attribute__((ext_vector_type(4))) float f32x4;

static __device__ __forceinline__ void gload_lds16(const void* g, void* l) {
  __builtin_amdgcn_global_load_lds((const __attribute__((address_space(1))) void*)g,
                                   (__attribute__((address_space(3))) void*)l, 16, 0, 0);
}

static __device__ __forceinline__ unsigned short f2bf(float f) {
  __hip_bfloat16 h = __float2bfloat16(f);
  unsigned short u;
  __builtin_memcpy(&u, &h, 2);
  return u;
}

static __device__ __forceinline__ float bf2f(unsigned short u) {
  unsigned int x = (unsigned int)u << 16;
  float f;
  __builtin_memcpy(&f, &x, 4);
  return f;
}

// ---------------- cast fp32 -> bf16, 8 elems/thread ----------------
__global__ __launch_bounds__(256) void cast_bf16_kernel(const float* __restrict__ in,
                                                        unsigned short* __restrict__ out,
                                                        int n8) {
  int idx = blockIdx.x * 256 + threadIdx.x;
  int stride = gridDim.x * 256;
  for (int i = idx; i < n8; i += stride) {
    const float4* p = (const float4*)in + (size_t)i * 2;
    float4 a = p[0], b = p[1];
    u16x8 r;
    r[0] = f2bf(a.x); r[1] = f2bf(a.y); r[2] = f2bf(a.z); r[3] = f2bf(a.w);
    r[4] = f2bf(b.x); r[5] = f2bf(b.y); r[6] = f2bf(b.z); r[7] = f2bf(b.w);
    *((u16x8*)out + i) = r;
  }
}

// ---------------- transpose + cast: W[K][N] fp32 -> Wt[N][K] bf16 ----------------
__global__ __launch_bounds__(256) void transpose_cast_kernel(const float* __restrict__ W,
                                                             unsigned short* __restrict__ Wt,
                                                             int K, int N) {
  __shared__ float tile[32][33];
  int n0 = blockIdx.x * 32, k0 = blockIdx.y * 32;
  int tx = threadIdx.x & 31, ty = threadIdx.x >> 5;
#pragma unroll
  for (int r = 0; r < 32; r += 8)
    tile[ty + r][tx] = W[(size_t)(k0 + ty + r) * N + n0 + tx];
  __syncthreads();
#pragma unroll
  for (int r = 0; r < 32; r += 8)
    Wt[(size_t)(n0 + ty + r) * K + k0 + tx] = f2bf(tile[tx][ty + r]);
}

// ---------------- GEMM: C[M,N] = A[M,K](bf16,row) * Bt[N,K](bf16,row)^T ----------------
// 128x128 tile, BK=64, 4 waves, each wave 64x64. XOR-swizzled LDS (pre-swizzled
// global source so global_load_lds stays linear).
// EPI 0: write Q layout [b(=row>>10)][h][n][64] bf16 into out0
// EPI 1: cols<1024 -> K [bh][m][64] into out0; cols>=1024 -> V^T [bh][d][m] into out1
// EPI 2: write fp32 outF[row*1024+col] = acc + bias[col]
template <int EPI>
__global__ __launch_bounds__(256, 2) void gemm_bt_kernel(
    const unsigned short* __restrict__ A, const unsigned short* __restrict__ Bt,
    int M, int N, int K,
    unsigned short* __restrict__ out0, unsigned short* __restrict__ out1,
    float* __restrict__ outF, const float* __restrict__ bias) {
  __shared__ unsigned short As[128 * 64];
  __shared__ unsigned short Bs[128 * 64];
  const int tid = threadIdx.x;
  const int l = tid & 63;
  const int lq = l & 15, g = l >> 4;
  const int w = tid >> 6;
  const int wr = w >> 1, wc = w & 1;
  const int m0 = blockIdx.y * 128, n0 = blockIdx.x * 128;

  f32x4 acc[4][4] = {};

  for (int k0 = 0; k0 < K; k0 += 64) {
    __syncthreads();
#pragma unroll
    for (int t = 0; t < 4; ++t) {
      int c = t * 256 + tid;
      int row = c >> 3, cb = c & 7;
      int srcoff = (cb * 16) ^ ((row & 7) << 4);
      char* la = (char*)As + t * 4096 + (tid & 192) * 16;  // wave-uniform base
      gload_lds16((const char*)(A + (size_t)(m0 + row) * K + k0) + srcoff, la);
      char* lb = (char*)Bs + t * 4096 + (tid & 192) * 16;
      gload_lds16((const char*)(Bt + (size_t)(n0 + row) * K + k0) + srcoff, lb);
    }
    __syncthreads();
#pragma unroll
    for (int ks = 0; ks < 2; ++ks) {
      short8 af[4], bfr[4];
#pragma unroll
      for (int mt = 0; mt < 4; ++mt) {
        int row = wr * 64 + mt * 16 + lq;
        af[mt] = *(const short8*)&As[row * 64 + ((ks * 32 + g * 8) ^ ((row & 7) << 3))];
      }
#pragma unroll
      for (int nt = 0; nt < 4; ++nt) {
        int row = wc * 64 + nt * 16 + lq;
        bfr[nt] = *(const short8*)&Bs[row * 64 + ((ks * 32 + g * 8) ^ ((row & 7) << 3))];
      }
#pragma unroll
      for (int mt = 0; mt < 4; ++mt)
#pragma unroll
        for (int nt = 0; nt < 4; ++nt)
          acc[mt][nt] =
              __builtin_amdgcn_mfma_f32_16x16x32_bf16(af[mt], bfr[nt], acc[mt][nt], 0, 0, 0);
    }
  }

#pragma unroll
  for (int mt = 0; mt < 4; ++mt) {
#pragma unroll
    for (int nt = 0; nt < 4; ++nt) {
      if (EPI == 1 && n0 >= 1024) {
        // V^T: [bh][d][m], 4 m-consecutive values packed per lane
        int colb = n0 - 1024 + wc * 64 + nt * 16 + lq;
        int h = colb >> 6, d = colb & 63;
        int rowb = m0 + wr * 64 + mt * 16 + g * 4;
        int b = rowb >> 12, mm = rowb & 4095;
        ushort4 pk;
        pk.x = f2bf(acc[mt][nt][0]);
        pk.y = f2bf(acc[mt][nt][1]);
        pk.z = f2bf(acc[mt][nt][2]);
        pk.w = f2bf(acc[mt][nt][3]);
        *(ushort4*)&out1[(((size_t)(b * 16 + h)) * 64 + d) * 4096 + mm] = pk;
      } else {
#pragma unroll
        for (int r = 0; r < 4; ++r) {
          int row = m0 + wr * 64 + mt * 16 + g * 4 + r;
          int col = n0 + wc * 64 + nt * 16 + lq;
          float v = acc[mt][nt][r];
          if (EPI == 0) {
            int b = row >> 10, nq = row & 1023;
            int h = col >> 6, d = col & 63;
            out0[(((size_t)(b * 16 + h)) * 1024 + nq) * 64 + d] = f2bf(v);
          } else if (EPI == 1) {
            int b = row >> 12, mm = row & 4095;
            int h = col >> 6, d = col & 63;
            out0[(((size_t)(b * 16 + h)) * 4096 + mm) * 64 + d] = f2bf(v);
          } else {
            outF[(size_t)row * 1024 + col] = v + bias[col];
          }
        }
      }
    }
  }
}

// ---------------- fused attention (j-split partials) ----------------
// Grid: 2048 linear blocks decoded XCD-affine: the 8 q-blocks sharing a
// (bh, j-split) K/V chunk map to the same XCD for L2 reuse.
// Block: 256 thr = 4 waves, each wave 32 q-rows. Each block covers 16 j-tiles
// (1024 j). Scores clipped to [-5,5] -> no running max needed; num and denom
// are additive over j -> partials combined by attn_reduce_kernel.
__global__ __launch_bounds__(256, 2) void attn_kernel(
    const unsigned short* __restrict__ Q, const unsigned short* __restrict__ Kb,
    const unsigned short* __restrict__ VbT, const int* __restrict__ mask,
    unsigned short* __restrict__ numP, float* __restrict__ denP) {
  __shared__ unsigned short Ks[64 * 64];      // [j][d], XOR-swizzled content
  __shared__ unsigned short Vt[64 * 64];      // [d][j], XOR-swizzled content
  __shared__ unsigned short Ps[4 * 32 * 64];  // per-wave [q][j], pswz-swizzled

  const int tid = threadIdx.x;
  const int l = tid & 63, w = tid >> 6;
  const int lq = l & 15, g = l >> 4;

  // XCD-affine decode: id&7 = XCD; 8 consecutive same-XCD blocks share (bh,js)
  const int id = blockIdx.x;
  const int xcd = id & 7;
  const int k = id >> 3;
  const int qi = k & 7;
  const int pr = xcd * 32 + (k >> 3);
  const int bh = pr & 63, js = pr >> 6;
  const int b = bh >> 4;
  const int q0 = qi * 128 + w * 32;

  const unsigned short* Qh = Q + (size_t)bh * 1024 * 64;
  const unsigned short* Kh = Kb + (size_t)bh * 4096 * 64;
  const unsigned short* Vth = VbT + (size_t)bh * 64 * 4096;
  const int* mb = mask + b * 4096;

  // Q fragments live in registers for the whole kernel
  short8 qf[2][2];
#pragma unroll
  for (int mt = 0; mt < 2; ++mt)
#pragma unroll
    for (int ks = 0; ks < 2; ++ks)
      qf[mt][ks] = *(const short8*)&Qh[(size_t)(q0 + mt * 16 + lq) * 64 + ks * 32 + g * 8];

  f32x4 acc[2][4] = {};
  float denom[2][4] = {};
  unsigned short* Pw = &Ps[w * 2048];

  const float SCALE2 = 0.18033688011112042f;  // 0.125 * log2(e)
  const float CLIP2 = 7.213475204444817f;     // 5 * log2(e)

  for (int jt = js * 16; jt < js * 16 + 16; ++jt) {
    const int j0 = jt * 64;
    __syncthreads();  // previous tile fully consumed
    // stage K tile [64 j][64 d] via global_load_lds, source pre-swizzled
#pragma unroll
    for (int t = 0; t < 2; ++t) {
      int c = t * 256 + tid;
      int row = c >> 3, cb = c & 7;
      int srcoff = (cb * 16) ^ ((row & 7) << 4);
      char* lk = (char*)Ks + t * 4096 + (tid & 192) * 16;
      gload_lds16((const char*)(Kh + (size_t)(j0 + row) * 64) + srcoff, lk);
    }
    // stage V^T tile [64 d][64 j] via global_load_lds from precomputed V^T
#pragma unroll
    for (int t = 0; t < 2; ++t) {
      int c = t * 256 + tid;
      int row = c >> 3, cb = c & 7;  // row = d
      int srcoff = (cb * 16) ^ ((row & 7) << 4);
      char* lv = (char*)Vt + t * 4096 + (tid & 192) * 16;
      gload_lds16((const char*)(Vth + (size_t)row * 4096 + j0) + srcoff, lv);
    }
    // per-lane mask for its j columns
    int mk[4];
#pragma unroll
    for (int nt = 0; nt < 4; ++nt) mk[nt] = mb[j0 + nt * 16 + lq];
    __syncthreads();

    // K fragments
    short8 kf[4][2];
#pragma unroll
    for (int nt = 0; nt < 4; ++nt) {
      int row = nt * 16 + lq;
#pragma unroll
      for (int ks = 0; ks < 2; ++ks)
        kf[nt][ks] = *(const short8*)&Ks[row * 64 + ((ks * 32 + g * 8) ^ ((row & 7) << 3))];
    }

    float tmp[2][4] = {};
#pragma unroll
    for (int mt = 0; mt < 2; ++mt) {
#pragma unroll
      for (int nt = 0; nt < 4; ++nt) {
        f32x4 s = {};
        s = __builtin_amdgcn_mfma_f32_16x16x32_bf16(qf[mt][0], kf[nt][0], s, 0, 0, 0);
        s = __builtin_amdgcn_mfma_f32_16x16x32_bf16(qf[mt][1], kf[nt][1], s, 0, 0, 0);
#pragma unroll
        for (int r = 0; r < 4; ++r) {
          float v = s[r] * SCALE2;
          v = fminf(fmaxf(v, -CLIP2), CLIP2);
          v = mk[nt] ? v : -CLIP2;  // masked -> exactly exp(-5), matches ref
          float pE = exp2f(v);
          tmp[mt][r] += pE;
          int q = mt * 16 + g * 4 + r;
          int j = nt * 16 + lq;
          int psw = (((q >> 2) & 3) << 4) ^ ((q & 7) << 3);
          Pw[q * 64 + (j ^ psw)] = f2bf(pE);
        }
      }
    }
    // denominator: reduce over the 16-lane j-group
#pragma unroll
    for (int mt = 0; mt < 2; ++mt)
#pragma unroll
      for (int r = 0; r < 4; ++r) {
        float v = tmp[mt][r];
        v += __shfl_xor(v, 1);
        v += __shfl_xor(v, 2);
        v += __shfl_xor(v, 4);
        v += __shfl_xor(v, 8);
        denom[mt][r] += v;
      }

    // PV
    short8 pa[2][2], vbf[4][2];
#pragma unroll
    for (int mt = 0; mt < 2; ++mt) {
      int row = mt * 16 + lq;
      int psw = (((row >> 2) & 3) << 4) ^ ((row & 7) << 3);
#pragma unroll
      for (int ks = 0; ks < 2; ++ks)
        pa[mt][ks] = *(const short8*)&Pw[row * 64 + ((ks * 32 + g * 8) ^ psw)];
    }
#pragma unroll
    for (int dt = 0; dt < 4; ++dt) {
      int row = dt * 16 + lq;
#pragma unroll
      for (int ks = 0; ks < 2; ++ks)
        vbf[dt][ks] = *(const short8*)&Vt[row * 64 + ((ks * 32 + g * 8) ^ ((row & 7) << 3))];
    }
#pragma unroll
    for (int mt = 0; mt < 2; ++mt)
#pragma unroll
      for (int dt = 0; dt < 4; ++dt) {
        acc[mt][dt] = __builtin_amdgcn_mfma_f32_16x16x32_bf16(pa[mt][0], vbf[dt][0], acc[mt][dt], 0, 0, 0);
        acc[mt][dt] = __builtin_amdgcn_mfma_f32_16x16x32_bf16(pa[mt][1], vbf[dt][1], acc[mt][dt], 0, 0, 0);
      }
  }

  // write partial numerator (bf16) and denominator (fp32)
#pragma unroll
  for (int mt = 0; mt < 2; ++mt)
#pragma unroll
    for (int dt = 0; dt < 4; ++dt)
#pragma unroll
      for (int r = 0; r < 4; ++r) {
        int q = q0 + mt * 16 + g * 4 + r;
        int d = dt * 16 + lq;
        numP[((((size_t)js * 64 + bh) * 1024 + q) * 64) + d] = f2bf(acc[mt][dt][r]);
      }
  if (lq == 0) {
#pragma unroll
    for (int mt = 0; mt < 2; ++mt)
#pragma unroll
      for (int r = 0; r < 4; ++r) {
        int q = q0 + mt * 16 + g * 4 + r;
        denP[(((size_t)js * 64 + bh) * 1024) + q] = denom[mt][r];
      }
  }
}

// ---------------- combine j-split partials, divide, write Ob ----------------
__global__ __launch_bounds__(256) void attn_reduce_kernel(
    const unsigned short* __restrict__ numP, const float* __restrict__ denP,
    unsigned short* __restrict__ Ob) {
  int id = blockIdx.x * 256 + threadIdx.x;  // 0 .. 524287
  int d8 = id & 7;
  int q = (id >> 3) & 1023;
  int bh = id >> 13;
  int b = bh >> 4, h = bh & 15;
  float den = 0.f;
  float o[8] = {0.f, 0.f, 0.f, 0.f, 0.f, 0.f, 0.f, 0.f};
#pragma unroll
  for (int s = 0; s < 4; ++s) {
    const unsigned short* np =
        numP + ((((size_t)s * 64 + bh) * 1024 + q) * 64 + d8 * 8);
    u16x8 v = *(const u16x8*)np;
    den += denP[((size_t)s * 64 + bh) * 1024 + q];
#pragma unroll
    for (int e = 0; e < 8; ++e) o[e] += bf2f(v[e]);
  }
  float r = 1.0f / den;
  u16x8 outv;
#pragma unroll
  for (int e = 0; e < 8; ++e) outv[e] = f2bf(o[e] * r);
  *(u16x8*)&Ob[(((size_t)b * 1024 + q) * 1024) + h * 64 + d8 * 8] = outv;
}

// ---------------- launcher ----------------
extern "C" void kernel_launch(void* const* d_in, const int* in_sizes, int n_in,
                              void* d_out, int out_size, void* d_ws, size_t ws_size,
                              hipStream_t stream) {
  (void)in_sizes; (void)n_in; (void)out_size; (void)ws_size;
  const float* x    = (const float*)d_in[0];
  const float* ctx  = (const float*)d_in[1];
  const int*   mask = (const int*)d_in[2];
  const float* Wq   = (const float*)d_in[3];
  const float* Wkv  = (const float*)d_in[4];
  const float* Wo   = (const float*)d_in[5];
  const float* bo   = (const float*)d_in[6];
  float* out = (float*)d_out;

  char* ws = (char*)d_ws;
  const size_t MB = 1 << 20;
  // 0..40 MiB region is time-shared: {xb, cb} before attention, {numP, denP} after
  unsigned short* numP = (unsigned short*)(ws + 0);        // 32 MiB : [4][64][1024][64] bf16
  float*          denP = (float*)(ws + 32 * MB);           // 1 MiB  : [4][64][1024] fp32
  unsigned short* xb   = (unsigned short*)(ws + 0);        // 8 MiB  : x bf16 [4096][1024]
  unsigned short* cb   = (unsigned short*)(ws + 8 * MB);   // 32 MiB : ctx bf16 [16384][1024]
  unsigned short* WqT  = (unsigned short*)(ws + 40 * MB);  // 2 MiB
  unsigned short* WkvT = (unsigned short*)(ws + 42 * MB);  // 4 MiB
  unsigned short* WoT  = (unsigned short*)(ws + 46 * MB);  // 2 MiB
  unsigned short* Qb   = (unsigned short*)(ws + 48 * MB);  // 8 MiB  : [bh][1024][64]
  unsigned short* Kb   = (unsigned short*)(ws + 56 * MB);  // 32 MiB : [bh][4096][64]
  unsigned short* VbT  = (unsigned short*)(ws + 88 * MB);  // 32 MiB : [bh][64][4096]
  unsigned short* Ob   = (unsigned short*)(ws + 120 * MB); // 8 MiB  : [b][n][1024]

  cast_bf16_kernel<<<2048, 256, 0, stream>>>(x, xb, (4 * 1024 * 1024) / 8);
  cast_bf16_kernel<<<2048, 256, 0, stream>>>(ctx, cb, (16 * 1024 * 1024) / 8);
  transpose_cast_kernel<<<dim3(32, 32), 256, 0, stream>>>(Wq, WqT, 1024, 1024);
  transpose_cast_kernel<<<dim3(64, 32), 256, 0, stream>>>(Wkv, WkvT, 1024, 2048);
  transpose_cast_kernel<<<dim3(32, 32), 256, 0, stream>>>(Wo, WoT, 1024, 1024);

  gemm_bt_kernel<0><<<dim3(8, 32), 256, 0, stream>>>(xb, WqT, 4096, 1024, 1024,
                                                     Qb, (unsigned short*)nullptr,
                                                     (float*)nullptr, (const float*)nullptr);
  gemm_bt_kernel<1><<<dim3(16, 128), 256, 0, stream>>>(cb, WkvT, 16384, 2048, 1024,
                                                       Kb, VbT,
                                                       (float*)nullptr, (const float*)nullptr);
  attn_kernel<<<2048, 256, 0, stream>>>(Qb, Kb, VbT, mask, numP, denP);
  attn_reduce_kernel<<<2048, 256, 0, stream>>>(numP, denP, Ob);
  gemm_bt_kernel<2><<<dim3(8, 32), 256, 0, stream>>>(Ob, WoT, 4096, 1024, 1024,
                                                     (unsigned short*)nullptr, (unsigned short*)nullptr,
                                                     out, bo);
}